// Round 1
// 239.639 us; speedup vs baseline: 1.0056x; 1.0056x over previous
//
#include <hip/hip_runtime.h>
#include <math.h>

// Problem constants
#define B_    8
#define L_    384
#define Q_    64
#define H_    256
#define R_    512          // B*Q rows
#define P_    73920        // L*(L+1)/2 pairs
#define NF4   18480        // P_/4 float4s per row
#define QF4   4620         // NF4/4 float4s per quarter-row block

// Workspace layout (float offsets). Total 1,463,552 floats = 5.86 MB.
// EXEY (written by k_prep) aliases W2/D/WB/E2 (dead after k_g) -- sequential kernels.
#define WS_EXEY  0          // 512*768
#define WS_W2    0          // 256*512 : W2[h][j], j = c*256+h'   (= Wq_c @ Wv_c^T)
#define WS_D     131072     // 512     : d[j]  = Wv_c[h',:] . bq_c
#define WS_WB    131584     // 512     : wb[c*256+h] = Wq[h, cH:] . bv_c
#define WS_E2    132096     // 2       : e_c = bq_c . bv_c
#define WS_TAB   393216     // 18480 u32 : packed (e<<16)|s per float4 index
#define WS_HIDT  411904     // 8*256*384 : hidT[b][h][v]
#define WS_G     1198336    // 512*512   : g[r][c*256+h']
#define WS_DOTC  1460480    // 512*2
#define WS_LOCS  1461504    // 512*2
#define WS_FACT  1462528    // 512*2

// ---------------------------------------------------------------- K0: setup
// grid = 294: [0,64) W2+wb (4 h-rows each), [64,101) decode table,
//             101 d+e2, [102,294) hidT transpose (8 b x 24 tiles)
__global__ __launch_bounds__(512) void k_setup(const float* __restrict__ hid,
                                               const float* __restrict__ Wq,
                                               const float* __restrict__ bq,
                                               const float* __restrict__ Wv,
                                               const float* __restrict__ bv,
                                               float* __restrict__ ws) {
    __shared__ float smem[64 * 65];
    int blk = blockIdx.x, tid = threadIdx.x;

    if (blk < 64) {
        // W2[h][c*256+h'] = sum_hp Wq[h][c*256+hp] * Wv[h'][c*256+hp]
        int h0 = blk * 4;
        int c = tid >> 8, hv = tid & 255;
        int cu = __builtin_amdgcn_readfirstlane(c);      // wave-uniform -> s_load path
        const float4* wv4  = reinterpret_cast<const float4*>(Wv + hv * 512 + cu * 256);
        const float4* wq40 = reinterpret_cast<const float4*>(Wq + (h0 + 0) * 512 + cu * 256);
        const float4* wq41 = reinterpret_cast<const float4*>(Wq + (h0 + 1) * 512 + cu * 256);
        const float4* wq42 = reinterpret_cast<const float4*>(Wq + (h0 + 2) * 512 + cu * 256);
        const float4* wq43 = reinterpret_cast<const float4*>(Wq + (h0 + 3) * 512 + cu * 256);
        float a0 = 0.f, a1 = 0.f, a2 = 0.f, a3 = 0.f;
        for (int k = 0; k < 64; k++) {
            float4 wv = wv4[k];
            float4 w0 = wq40[k]; a0 += wv.x * w0.x + wv.y * w0.y + wv.z * w0.z + wv.w * w0.w;
            float4 w1 = wq41[k]; a1 += wv.x * w1.x + wv.y * w1.y + wv.z * w1.z + wv.w * w1.w;
            float4 w2 = wq42[k]; a2 += wv.x * w2.x + wv.y * w2.y + wv.z * w2.z + wv.w * w2.w;
            float4 w3 = wq43[k]; a3 += wv.x * w3.x + wv.y * w3.y + wv.z * w3.z + wv.w * w3.w;
        }
        ws[WS_W2 + (h0 + 0) * 512 + tid] = a0;
        ws[WS_W2 + (h0 + 1) * 512 + tid] = a1;
        ws[WS_W2 + (h0 + 2) * 512 + tid] = a2;
        ws[WS_W2 + (h0 + 3) * 512 + tid] = a3;
        // wb[c][h] = Wq[h, cH:cH+256] . bv_c
        if (tid < 128) {
            int c2 = tid >> 6, lane = tid & 63;
#pragma unroll
            for (int hh = 0; hh < 4; hh++) {
                float v = 0.f;
#pragma unroll
                for (int k2 = 0; k2 < 4; k2++) {
                    int hp = lane + 64 * k2;
                    v += Wq[(h0 + hh) * 512 + c2 * 256 + hp] * bv[c2 * 256 + hp];
                }
#pragma unroll
                for (int off = 32; off; off >>= 1) v += __shfl_xor(v, off);
                if (lane == 0) ws[WS_WB + c2 * 256 + h0 + hh] = v;
            }
        }
    } else if (blk < 101) {
        // triangular decode table: idx -> (e, s) of element p0 = idx*4
        int idx = (blk - 64) * 512 + tid;
        if (idx < NF4) {
            int p0 = idx << 2;
            int e = (int)((sqrtf(8.f * (float)p0 + 1.f) - 1.f) * 0.5f);
            int tri = (e * (e + 1)) >> 1;
            while (tri > p0) { e--; tri -= (e + 1); }
            while (p0 - tri > e) { tri += (e + 1); e++; }
            int s = p0 - tri;
            reinterpret_cast<unsigned*>(ws)[WS_TAB + idx] = ((unsigned)e << 16) | (unsigned)s;
        }
    } else if (blk == 101) {
        // d[j] = Wv[h', cH:] . bq_c ;  e_c = bq_c . bv_c
        int c = tid >> 8, hv = tid & 255;
        int cu = __builtin_amdgcn_readfirstlane(c);
        const float4* wv4 = reinterpret_cast<const float4*>(Wv + hv * 512 + cu * 256);
        const float4* bq4 = reinterpret_cast<const float4*>(bq + cu * 256);
        float a = 0.f;
        for (int k = 0; k < 64; k++) {
            float4 wv = wv4[k]; float4 b4 = bq4[k];
            a += wv.x * b4.x + wv.y * b4.y + wv.z * b4.z + wv.w * b4.w;
        }
        ws[WS_D + tid] = a;
        if (tid < 128) {
            int c2 = tid >> 6, lane = tid & 63;
            float v = 0.f;
#pragma unroll
            for (int k2 = 0; k2 < 4; k2++) {
                int hp = lane + 64 * k2;
                v += bq[c2 * 256 + hp] * bv[c2 * 256 + hp];
            }
#pragma unroll
            for (int off = 32; off; off >>= 1) v += __shfl_xor(v, off);
            if (lane == 0) ws[WS_E2 + c2] = v;
        }
    } else {
        // hidT transpose, 64x64 tiles, 512 threads (8 rows/pass)
        int t = blk - 102;
        int b = t / 24, tt = t % 24;
        int mt = tt % 6, nt = tt / 6;               // M=384 (v), N=256 (h)
        const float* in = hid + b * 98304;
        float* outp = ws + WS_HIDT + b * 98304;
        float (*tsm)[65] = (float(*)[65])smem;
        int lane = tid & 63, row8 = tid >> 6;
        int m0 = mt * 64, n0 = nt * 64;
#pragma unroll
        for (int p = 0; p < 8; p++) {
            int mr = p * 8 + row8;
            tsm[mr][lane] = in[(m0 + mr) * 256 + n0 + lane];
        }
        __syncthreads();
#pragma unroll
        for (int p = 0; p < 8; p++) {
            int nr = p * 8 + row8;
            outp[(n0 + nr) * 384 + m0 + lane] = tsm[lane][nr];
        }
    }
}

// ---------------------------------------------------------------- K1: g = q@W2 + d, dotc, small heads
// grid = 256 (2 rows each), 512 threads. No LDS; q operand is wave-uniform -> SGPR.
__global__ __launch_bounds__(512) void k_g(const float* __restrict__ queries,
                                           const float* __restrict__ qlocs,
                                           const float* __restrict__ qlogits,
                                           const float* __restrict__ Wc,
                                           const float* __restrict__ bc,
                                           const float* __restrict__ Wo,
                                           const float* __restrict__ bo,
                                           const float* __restrict__ Wf,
                                           const float* __restrict__ bf,
                                           float* __restrict__ ws,
                                           float* __restrict__ out) {
    int tid = threadIdx.x;
    int r0 = blockIdx.x * 2;

    // Phase A: g[r][j] = sum_h q[r][h] * W2[h][j] + d[j]   (q via s_load, W2 coalesced)
    {
        const float* qa = queries + r0 * 256;
        const float* qb = qa + 256;
        const float* w2 = ws + WS_W2 + tid;
        float a0 = 0.f, a1 = 0.f;
#pragma unroll 8
        for (int h = 0; h < 256; h++) {
            float w = w2[h * 512];
            a0 += qa[h] * w;
            a1 += qb[h] * w;
        }
        float dj = ws[WS_D + tid];
        ws[WS_G + r0 * 512 + tid]       = a0 + dj;
        ws[WS_G + (r0 + 1) * 512 + tid] = a1 + dj;
    }

    int w = tid >> 6, lane = tid & 63;
    if (w < 4) {
        // dotc[r][c] = q[r] . wb_c + e_c
        int r = r0 + (w >> 1), c = w & 1;
        float v = 0.f;
#pragma unroll
        for (int k = 0; k < 4; k++) {
            int h = lane + 64 * k;
            v += queries[r * 256 + h] * ws[WS_WB + c * 256 + h];
        }
#pragma unroll
        for (int off = 32; off; off >>= 1) v += __shfl_xor(v, off);
        if (lane == 0) ws[WS_DOTC + r * 2 + c] = v + ws[WS_E2 + c];
    } else if (w < 6) {
        // small heads: labels softmax, locs offset, softplus factors
        int r = r0 + (w - 4);
        const float* qr = queries + r * 256;
        float q0 = qr[lane], q1 = qr[lane + 64], q2 = qr[lane + 128], q3 = qr[lane + 192];

        float x[10];
#pragma unroll
        for (int t = 0; t < 10; t++) {
            float v = q0 * Wc[lane * 10 + t] + q1 * Wc[(lane + 64) * 10 + t]
                    + q2 * Wc[(lane + 128) * 10 + t] + q3 * Wc[(lane + 192) * 10 + t];
#pragma unroll
            for (int off = 32; off; off >>= 1) v += __shfl_xor(v, off);
            x[t] = qlogits[r * 10 + t] + bc[t] + v;
        }
        float m = -1e30f;
#pragma unroll
        for (int t = 0; t < 10; t++) m = fmaxf(m, x[t]);
        float s = 0.f;
#pragma unroll
        for (int t = 0; t < 10; t++) { x[t] = expf(x[t] - m); s += x[t]; }
        float inv = 1.0f / s;
        if (lane == 0) {
#pragma unroll
            for (int t = 0; t < 10; t++) out[r * 10 + t] = x[t] * inv;
        }

#pragma unroll
        for (int k = 0; k < 2; k++) {
            float vo = q0 * Wo[lane * 2 + k] + q1 * Wo[(lane + 64) * 2 + k]
                     + q2 * Wo[(lane + 128) * 2 + k] + q3 * Wo[(lane + 192) * 2 + k];
            float vf = q0 * Wf[lane * 2 + k] + q1 * Wf[(lane + 64) * 2 + k]
                     + q2 * Wf[(lane + 128) * 2 + k] + q3 * Wf[(lane + 192) * 2 + k];
#pragma unroll
            for (int off = 32; off; off >>= 1) { vo += __shfl_xor(vo, off); vf += __shfl_xor(vf, off); }
            if (lane == 0) {
                ws[WS_LOCS + r * 2 + k] = qlocs[r * 2 + k] + vo + bo[k];
                float xx = vf + bf[k];
                ws[WS_FACT + r * 2 + k] = (xx > 20.f) ? xx : log1pf(expf(xx));
            }
        }
    }
}

// ---------------------------------------------------------------- K2: scores -> factorized softmax prep
// block = 384 threads (6 waves), grid = 512 (one row each). g via uniform s_load (no LDS broadcast).
__global__ __launch_bounds__(384) void k_prep(const float* __restrict__ ws_c,
                                              float* __restrict__ ws,
                                              const int* __restrict__ mask) {
    __shared__ float s0[384], s1[384];
    __shared__ float Ex[384], Ey[384];
    __shared__ float scal[4];

    int tid = threadIdx.x;
    int r = blockIdx.x;                         // grid = 512
    int b = r >> 6;

    const float* gp = ws_c + WS_G + r * 512;    // uniform base -> scalar loads
    float dotc0 = ws_c[WS_DOTC + r * 2 + 0];
    float dotc1 = ws_c[WS_DOTC + r * 2 + 1];
    float lx = ws_c[WS_LOCS + r * 2 + 0], ly = ws_c[WS_LOCS + r * 2 + 1];
    float fx = ws_c[WS_FACT + r * 2 + 0], fy = ws_c[WS_FACT + r * 2 + 1];

    // scores for v = tid (0..383)
    const float* hT = ws_c + WS_HIDT + b * 98304;
    float s0r, s1r;
    bool mk;
    {
        int v = tid;
        float a0 = 0.f, a1 = 0.f;
        const float* p = hT + v;
#pragma unroll 8
        for (int h = 0; h < 256; h++) {
            float x = p[h * 384];
            a0 += x * gp[h];
            a1 += x * gp[256 + h];
        }
        mk = mask[b * 384 + v] != 0;
        s0r = mk ? (a0 + dotc0) * 0.0625f : -1e8f;
        s1r = mk ? (a1 + dotc1) * 0.0625f : -1e8f;
        s0[v] = s0r;
        s1[v] = s1r;
    }
    __syncthreads();

    // wave 0: prefix-max of s0, then mM = max_e(s1+pm), m1 = max s1, m0 = max s0
    if (tid < 64) {
        int l = tid;
        float p[6];
        p[0] = s0[l * 6 + 0];
#pragma unroll
        for (int k = 1; k < 6; k++) p[k] = fmaxf(p[k - 1], s0[l * 6 + k]);
        float run = p[5];
#pragma unroll
        for (int off = 1; off < 64; off <<= 1) {
            float t = __shfl_up(run, off);
            if (l >= off) run = fmaxf(run, t);
        }
        float excl = __shfl_up(run, 1);
        if (l == 0) excl = -1e30f;
        float m0 = __shfl(run, 63);
        float lm = -1e30f, lm1 = -1e30f;
#pragma unroll
        for (int k = 0; k < 6; k++) {
            float pm = fmaxf(excl, p[k]);
            float sv = s1[l * 6 + k];
            lm = fmaxf(lm, sv + pm);
            lm1 = fmaxf(lm1, sv);
        }
#pragma unroll
        for (int off = 1; off < 64; off <<= 1) {
            lm  = fmaxf(lm,  __shfl_xor(lm,  off));
            lm1 = fmaxf(lm1, __shfl_xor(lm1, off));
        }
        if (l == 0) { scal[0] = m0; scal[1] = lm1; scal[2] = lm; }
    }
    __syncthreads();

    // Ex, Ey (elementwise, i = tid)
    float m0 = scal[0], m1 = scal[1], mM = scal[2];
    float exv, eyv;
    {
        int i = tid;
        float ds = (float)i - lx;
        exv = expf(s0r - m0 - fx * ds * ds);
        float de = (float)i - ly;
        eyv = mk ? expf(s1r - m1 - fy * de * de) : 0.f;
        Ex[i] = exv;
        Ey[i] = eyv;
    }
    __syncthreads();

    // wave 0: prefix-sum of Ex, S2 = sum_e Ey[e]*psum[e], scale
    if (tid < 64) {
        int l = tid;
        float p[6];
        p[0] = Ex[l * 6 + 0];
#pragma unroll
        for (int k = 1; k < 6; k++) p[k] = p[k - 1] + Ex[l * 6 + k];
        float run = p[5];
#pragma unroll
        for (int off = 1; off < 64; off <<= 1) {
            float t = __shfl_up(run, off);
            if (l >= off) run += t;
        }
        float excl = __shfl_up(run, 1);
        if (l == 0) excl = 0.f;
        float s2l = 0.f;
#pragma unroll
        for (int k = 0; k < 6; k++)
            s2l += Ey[l * 6 + k] * (excl + p[k]);
#pragma unroll
        for (int off = 1; off < 64; off <<= 1) s2l += __shfl_xor(s2l, off);
        if (l == 0) {
            float C = expf(m0 + m1 - mM);
            scal[3] = C / (C * s2l + 1e-12f);
        }
    }
    __syncthreads();

    float scale = scal[3];
    float* exr = ws + WS_EXEY + r * 768;
    exr[tid]       = exv;
    exr[384 + tid] = eyv * scale;
}

// ---------------------------------------------------------------- K3: stream writes  out[p] = Ex[s]*Ey[e]
// Table-driven decode + 4 shifted Ex copies in LDS -> aligned conflict-free ds_read_b128.
__global__ __launch_bounds__(256) void k_write(const float* __restrict__ ws,
                                               float* __restrict__ out) {
    __shared__ alignas(16) float exsh[4][384];   // exsh[c][k] = Ex[k+c]
    __shared__ float eysh[384];
    int tid = threadIdx.x;
    int r = blockIdx.x >> 2, q = blockIdx.x & 3;   // grid = 2048
    const float* exr = ws + WS_EXEY + r * 768;
    for (int i = tid; i < 768; i += 256) {
        float v = exr[i];
        if (i < 384) {
#pragma unroll
            for (int c = 0; c < 4; c++)
                if (i >= c) exsh[c][i - c] = v;
        } else {
            eysh[i - 384] = v;
        }
    }
    __syncthreads();

    const unsigned* tab = reinterpret_cast<const unsigned*>(ws) + WS_TAB;
    float* ob = out + 5120 + r * 73920;
    int base = q * QF4;
    int end = base + QF4;
    for (int idx = base + tid; idx < end; idx += 256) {
        unsigned t = tab[idx];
        int e = (int)(t >> 16), s = (int)(t & 0xffffu);
        float4 v;
        if (s + 3 <= e) {
            // all 4 elements within row e: one aligned float4 from the shifted copy
            float ey = eysh[e];
            const float4* p4 = reinterpret_cast<const float4*>(&exsh[s & 3][s & ~3]);
            float4 ex = *p4;
            v.x = ex.x * ey; v.y = ex.y * ey; v.z = ex.z * ey; v.w = ex.w * ey;
        } else {
            int ss = s, ee = e;
            float ey = eysh[ee];
            v.x = exsh[0][ss] * ey; if (++ss > ee) { ss = 0; ey = eysh[++ee]; }
            v.y = exsh[0][ss] * ey; if (++ss > ee) { ss = 0; ey = eysh[++ee]; }
            v.z = exsh[0][ss] * ey; if (++ss > ee) { ss = 0; ey = eysh[++ee]; }
            v.w = exsh[0][ss] * ey;
        }
        reinterpret_cast<float4*>(ob)[idx] = v;
    }
}

// ---------------------------------------------------------------- launch
extern "C" void kernel_launch(void* const* d_in, const int* in_sizes, int n_in,
                              void* d_out, int out_size, void* d_ws, size_t ws_size,
                              hipStream_t stream) {
    const float* hiddens = (const float*)d_in[0];
    const int* masks     = (const int*)d_in[1];   // jax bool -> int32 in harness
    const float* queries = (const float*)d_in[2];
    const float* qlocs   = (const float*)d_in[3];
    const float* qlogits = (const float*)d_in[4];
    const float* Wc = (const float*)d_in[5];
    const float* bc = (const float*)d_in[6];
    const float* Wq = (const float*)d_in[7];
    const float* bq = (const float*)d_in[8];
    const float* Wv = (const float*)d_in[9];
    const float* bv = (const float*)d_in[10];
    const float* Wo = (const float*)d_in[11];
    const float* bo = (const float*)d_in[12];
    const float* Wf = (const float*)d_in[13];
    const float* bf = (const float*)d_in[14];
    float* out = (float*)d_out;
    float* ws  = (float*)d_ws;     // needs 5.86 MB

    hipLaunchKernelGGL(k_setup, dim3(294),  dim3(512), 0, stream, hiddens, Wq, bq, Wv, bv, ws);
    hipLaunchKernelGGL(k_g,     dim3(256),  dim3(512), 0, stream,
                       queries, qlocs, qlogits, Wc, bc, Wo, bo, Wf, bf, ws, out);
    hipLaunchKernelGGL(k_prep,  dim3(512),  dim3(384), 0, stream, ws, ws, masks);
    hipLaunchKernelGGL(k_write, dim3(2048), dim3(256), 0, stream, ws, out);
}